// Round 5
// baseline (229.094 us; speedup 1.0000x reference)
//
#include <hip/hip_runtime.h>
#include <math.h>

#define BB 16
#define CC 128
#define TT 1024
#define KK 7
#define DK 64
#define NSPLIT 4

typedef float f32x4 __attribute__((ext_vector_type(4)));
typedef short s16x8 __attribute__((ext_vector_type(8)));

__device__ inline short f2bf(float f) {
  union { float f; unsigned u; } v; v.f = f;
  unsigned r = (v.u + 0x7FFFu + ((v.u >> 16) & 1u)) >> 16;
  return (short)r;
}
__device__ inline float bf2f(short s) {
  union { unsigned u; float f; } v;
  v.u = ((unsigned)(unsigned short)s) << 16;
  return v.f;
}

// block-wide (256 threads) reduce of (s,ss) -> dst[0..1]
__device__ inline void block_partial_256(float s, float ss, float* dst) {
#pragma unroll
  for (int off = 32; off; off >>= 1) { s += __shfl_xor(s, off); ss += __shfl_xor(ss, off); }
  __shared__ float red[8];
  int w = threadIdx.x >> 6;
  if ((threadIdx.x & 63) == 0) { red[2 * w] = s; red[2 * w + 1] = ss; }
  __syncthreads();
  if (threadIdx.x == 0) {
    for (int i = 1; i < 4; ++i) { s += red[2 * i]; ss += red[2 * i + 1]; }
    dst[0] = s; dst[1] = ss;
  }
}

__device__ inline void ln_stats_from_parts(const float* part_batch, int n, float* sh) {
  if (threadIdx.x < 64) {
    float s = 0.f, ss = 0.f;
    for (int i = threadIdx.x; i < n; i += 64) { s += part_batch[2 * i]; ss += part_batch[2 * i + 1]; }
#pragma unroll
    for (int off = 32; off; off >>= 1) { s += __shfl_xor(s, off); ss += __shfl_xor(ss, off); }
    if (threadIdx.x == 0) {
      const float invN = 1.f / (float)(CC * TT);
      float mu = s * invN;
      sh[0] = mu;
      sh[1] = rsqrtf(ss * invN - mu * mu + 1e-5f);
    }
  }
  __syncthreads();
}

// ---------------- one-time prep: weights + LN params -> bf16 ----------------
// lnpb layout: [n0g | n0b | nsg(4) | nsb(4) | neg | neb], each 131072
__global__ __launch_bounds__(256) void k_prep(const float* __restrict__ pww,
                                              const float* __restrict__ Wq,
                                              const float* __restrict__ Wk,
                                              const float* __restrict__ Wv,
                                              const float* __restrict__ Wo,
                                              const float* __restrict__ fcw,
                                              const float* __restrict__ n0g,
                                              const float* __restrict__ n0b,
                                              const float* __restrict__ nsg,
                                              const float* __restrict__ nsb,
                                              const float* __restrict__ neg_,
                                              const float* __restrict__ neb,
                                              short* __restrict__ pwwb,
                                              short* __restrict__ wqkvb,
                                              short* __restrict__ wo2b,
                                              short* __restrict__ fcwb,
                                              short* __restrict__ lnpb) {
  int i = blockIdx.x * 256 + threadIdx.x;  // weights: 114688, LN: 1572864
  if (i < 65536) { pwwb[i] = f2bf(pww[i]); return; }
  i -= 65536;
  if (i < 24576) {
    int m = i >> 7, c = i & 127;
    int sel = m >> 6, d = m & 63;
    const float* srcp = sel == 0 ? Wq : (sel == 1 ? Wk : Wv);
    wqkvb[i] = f2bf(srcp[c * DK + d]);
    return;
  }
  i -= 24576;
  if (i < 8192) {
    int o = i >> 6, d = i & 63;
    wo2b[i] = f2bf(Wo[d * CC + o] + Wo[(d + 64) * CC + o]);
    return;
  }
  i -= 8192;
  if (i < 16384) { fcwb[i] = f2bf(fcw[i]); return; }
  i -= 16384;
  if (i >= 1572864) return;
  const int CT = CC * TT;  // 131072
  float v;
  if (i < CT) v = n0g[i];
  else if (i < 2 * CT) v = n0b[i - CT];
  else if (i < 6 * CT) v = nsg[i - 2 * CT];
  else if (i < 10 * CT) v = nsb[i - 6 * CT];
  else if (i < 11 * CT) v = neg_[i - 10 * CT];
  else v = neb[i - 11 * CT];
  lnpb[i] = f2bf(v);
}

// ---------------- pos encoding + add -> bf16 (+ LN partials) ----------------
__global__ __launch_bounds__(256) void k_addpos(const float* __restrict__ x,
                                                short* __restrict__ out,
                                                float* __restrict__ part) {
  int bc = blockIdx.x;  // b*CC + c
  int c = bc & (CC - 1);
  float ce = (float)(c & ~1);
  float freq = expf(-(ce / (float)CC) * 9.210340371976184f);
  float phase = (c & 1) ? 1.5707963267948966f : 0.0f;
  const float4* xr = (const float4*)(x + (size_t)bc * TT);
  short* orow = out + (size_t)bc * TT;
  int t = threadIdx.x * 4;
  float4 xv = xr[threadIdx.x];
  float v0 = xv.x + sinf((float)t * freq + phase);
  float v1 = xv.y + sinf((float)(t + 1) * freq + phase);
  float v2 = xv.z + sinf((float)(t + 2) * freq + phase);
  float v3 = xv.w + sinf((float)(t + 3) * freq + phase);
  float s = v0 + v1 + v2 + v3;
  float ss = v0 * v0 + v1 * v1 + v2 * v2 + v3 * v3;
  short4 o; o.x = f2bf(v0); o.y = f2bf(v1); o.z = f2bf(v2); o.w = f2bf(v3);
  *(short4*)(orow + t) = o;
  block_partial_256(s, ss, part + (size_t)bc * 2);
}

// ------- dsconv: [LN-in] depthwise(fp32) -> MFMA pointwise + relu + [LN-res] residual -------
template <bool LN_IN, bool LN_RES>
__global__ __launch_bounds__(256) void k_dsconv(const short* __restrict__ in,
                                                const short* __restrict__ lng,
                                                const short* __restrict__ lnb,
                                                const float* __restrict__ part_in, int npart,
                                                const float* __restrict__ dww,
                                                const float* __restrict__ dwb,
                                                const short* __restrict__ pwwb,
                                                const float* __restrict__ pwb,
                                                short* __restrict__ out,
                                                float* __restrict__ part_out) {
  int tile = blockIdx.x & 31, b = blockIdx.x >> 5;
  int t0 = tile * 32;
  __shared__ float stats[2];
  __shared__ float xs[CC][39];
  __shared__ __align__(16) short Dt[32][136];
  ln_stats_from_parts(part_in + (size_t)b * npart * 2, npart, stats);
  float mu = stats[0], rs = stats[1];

  for (int i = threadIdx.x; i < CC * 38; i += 256) {
    int c = i / 38, j = i - c * 38;
    int t = t0 + j - 3;
    float v = 0.f;
    if (t >= 0 && t < TT) {
      v = bf2f(in[((size_t)b * CC + c) * TT + t]);
      if (LN_IN) v = (v - mu) * rs * bf2f(lng[c * TT + t]) + bf2f(lnb[c * TT + t]);
    }
    xs[c][j] = v;
  }
  __syncthreads();
  for (int i = threadIdx.x; i < 32 * CC; i += 256) {
    int t = i >> 7, c = i & 127;
    float a = dwb[c];
#pragma unroll
    for (int j = 0; j < KK; ++j) a += dww[c * KK + j] * xs[c][t + j];
    Dt[t][c] = f2bf(a);
  }
  __syncthreads();

  int w = threadIdx.x >> 6, lane = threadIdx.x & 63;
  int lo = lane & 15, hi = lane >> 4;
  f32x4 acc[2][2];
#pragma unroll
  for (int mt = 0; mt < 2; ++mt)
#pragma unroll
    for (int nt = 0; nt < 2; ++nt) { acc[mt][nt][0] = 0.f; acc[mt][nt][1] = 0.f; acc[mt][nt][2] = 0.f; acc[mt][nt][3] = 0.f; }
#pragma unroll
  for (int ks = 0; ks < 4; ++ks) {
    s16x8 b0 = *(const s16x8*)&Dt[lo][ks * 32 + hi * 8];
    s16x8 b1 = *(const s16x8*)&Dt[16 + lo][ks * 32 + hi * 8];
    s16x8 a0 = *(const s16x8*)&pwwb[(size_t)(w * 32 + lo) * CC + ks * 32 + hi * 8];
    s16x8 a1 = *(const s16x8*)&pwwb[(size_t)(w * 32 + 16 + lo) * CC + ks * 32 + hi * 8];
    acc[0][0] = __builtin_amdgcn_mfma_f32_16x16x32_bf16(a0, b0, acc[0][0], 0, 0, 0);
    acc[0][1] = __builtin_amdgcn_mfma_f32_16x16x32_bf16(a0, b1, acc[0][1], 0, 0, 0);
    acc[1][0] = __builtin_amdgcn_mfma_f32_16x16x32_bf16(a1, b0, acc[1][0], 0, 0, 0);
    acc[1][1] = __builtin_amdgcn_mfma_f32_16x16x32_bf16(a1, b1, acc[1][1], 0, 0, 0);
  }

  float s = 0.f, ss = 0.f;
#pragma unroll
  for (int mt = 0; mt < 2; ++mt)
#pragma unroll
    for (int nt = 0; nt < 2; ++nt)
#pragma unroll
      for (int r = 0; r < 4; ++r) {
        int row = w * 32 + mt * 16 + hi * 4 + r;
        int t = t0 + nt * 16 + lo;
        float v = acc[mt][nt][r] + pwb[row];
        v = v > 0.f ? v : 0.f;
        size_t idx = ((size_t)b * CC + row) * TT + t;
        float rv = bf2f(in[idx]);
        if (LN_RES) rv = (rv - mu) * rs * bf2f(lng[row * TT + t]) + bf2f(lnb[row * TT + t]);
        v += rv;
        out[idx] = f2bf(v);
        s += v; ss += v * v;
      }
  block_partial_256(s, ss, part_out + (size_t)blockIdx.x * 2);
}

// ---------------- q,k,v projections: MFMA, M=192 stacked ----------------
__global__ __launch_bounds__(256) void k_qkv(const short* __restrict__ in,
                                             const short* __restrict__ lng,
                                             const short* __restrict__ lnb,
                                             const float* __restrict__ part_in,
                                             const short* __restrict__ wqkvb,
                                             short* __restrict__ q,
                                             short* __restrict__ k,
                                             short* __restrict__ vt) {
  int tile = blockIdx.x & 31, b = blockIdx.x >> 5;
  int t0 = tile * 32;
  __shared__ float stats[2];
  __shared__ __align__(16) short Dt[32][136];
  ln_stats_from_parts(part_in + (size_t)b * 64, 32, stats);
  float mu = stats[0], rs = stats[1];
  for (int i = threadIdx.x; i < CC * 16; i += 256) {
    int c = i >> 4, t2 = (i & 15) * 2;
    size_t base = ((size_t)b * CC + c) * TT + t0 + t2;
    unsigned u = *(const unsigned*)(in + base);
    unsigned g = *(const unsigned*)(lng + c * TT + t0 + t2);
    unsigned bb2 = *(const unsigned*)(lnb + c * TT + t0 + t2);
    float v0 = (bf2f((short)(u & 0xFFFF)) - mu) * rs * bf2f((short)(g & 0xFFFF)) + bf2f((short)(bb2 & 0xFFFF));
    float v1 = (bf2f((short)(u >> 16)) - mu) * rs * bf2f((short)(g >> 16)) + bf2f((short)(bb2 >> 16));
    Dt[t2][c] = f2bf(v0);
    Dt[t2 + 1][c] = f2bf(v1);
  }
  __syncthreads();

  int w = threadIdx.x >> 6, lane = threadIdx.x & 63;
  int lo = lane & 15, hi = lane >> 4;
  f32x4 acc[3][2];
#pragma unroll
  for (int mt = 0; mt < 3; ++mt)
#pragma unroll
    for (int nt = 0; nt < 2; ++nt) { acc[mt][nt][0] = 0.f; acc[mt][nt][1] = 0.f; acc[mt][nt][2] = 0.f; acc[mt][nt][3] = 0.f; }
#pragma unroll
  for (int ks = 0; ks < 4; ++ks) {
    s16x8 b0 = *(const s16x8*)&Dt[lo][ks * 32 + hi * 8];
    s16x8 b1 = *(const s16x8*)&Dt[16 + lo][ks * 32 + hi * 8];
#pragma unroll
    for (int mt = 0; mt < 3; ++mt) {
      s16x8 a = *(const s16x8*)&wqkvb[(size_t)(w * 48 + mt * 16 + lo) * CC + ks * 32 + hi * 8];
      acc[mt][0] = __builtin_amdgcn_mfma_f32_16x16x32_bf16(a, b0, acc[mt][0], 0, 0, 0);
      acc[mt][1] = __builtin_amdgcn_mfma_f32_16x16x32_bf16(a, b1, acc[mt][1], 0, 0, 0);
    }
  }
#pragma unroll
  for (int mt = 0; mt < 3; ++mt)
#pragma unroll
    for (int nt = 0; nt < 2; ++nt) {
      int m0 = w * 48 + mt * 16 + hi * 4;
      int t = t0 + nt * 16 + lo;
      short4 pk;
      pk.x = f2bf(acc[mt][nt][0]); pk.y = f2bf(acc[mt][nt][1]);
      pk.z = f2bf(acc[mt][nt][2]); pk.w = f2bf(acc[mt][nt][3]);
      if (m0 < 64) {
        *(short4*)(q + ((size_t)b * TT + t) * DK + m0) = pk;
      } else if (m0 < 128) {
        *(short4*)(k + ((size_t)b * TT + t) * DK + (m0 - 64)) = pk;
      } else {
        int d = m0 - 128;
        vt[((size_t)b * DK + d) * TT + t] = pk.x;
        vt[((size_t)b * DK + d + 1) * TT + t] = pk.y;
        vt[((size_t)b * DK + d + 2) * TT + t] = pk.z;
        vt[((size_t)b * DK + d + 3) * TT + t] = pk.w;
      }
    }
}

// ---------------- flash attention, split-K -> bf16 partials ----------------
__global__ __launch_bounds__(128) void k_attn(const short* __restrict__ qb,
                                              const short* __restrict__ kbuf,
                                              const short* __restrict__ vtb,
                                              const float* __restrict__ mask,
                                              short* __restrict__ pacc,
                                              float* __restrict__ pml) {
  int sp = blockIdx.x & (NSPLIT - 1);
  int qt = (blockIdx.x >> 2) & 31;
  int b = blockIdx.x >> 7;
  int w = threadIdx.x >> 6, lane = threadIdx.x & 63;
  int lo = lane & 15, hi = lane >> 4;

  __shared__ __align__(16) short ks[64][72];
  __shared__ __align__(16) short vt[64][72];
  __shared__ __align__(16) short ps[2][16][68];
  __shared__ float ms[64];

  const short* qp = qb + ((size_t)b * TT + qt * 32 + w * 16 + lo) * DK + hi * 8;
  s16x8 aq0 = *(const s16x8*)qp;
  s16x8 aq1 = *(const s16x8*)(qp + 32);

  f32x4 acc[4];
  float m_i[4], l_i[4];
#pragma unroll
  for (int r = 0; r < 4; ++r) {
    m_i[r] = -3.0e38f; l_i[r] = 0.f;
#pragma unroll
    for (int nt = 0; nt < 4; ++nt) acc[nt][r] = 0.f;
  }
  const float scale = 0.125f;

  for (int kb2 = sp * (TT / 64 / NSPLIT); kb2 < (sp + 1) * (TT / 64 / NSPLIT); ++kb2) {
    __syncthreads();
    for (int i = threadIdx.x; i < 512; i += 128) {
      int r = i >> 3, ch = i & 7;
      *(s16x8*)&ks[r][ch * 8] =
          *(const s16x8*)(kbuf + ((size_t)b * TT + kb2 * 64 + r) * DK + ch * 8);
      *(s16x8*)&vt[r][ch * 8] =
          *(const s16x8*)(vtb + ((size_t)b * DK + r) * TT + kb2 * 64 + ch * 8);
    }
    if (threadIdx.x < 64) ms[threadIdx.x] = mask[(size_t)b * TT + kb2 * 64 + threadIdx.x];
    __syncthreads();

    f32x4 sc[4];
#pragma unroll
    for (int nt = 0; nt < 4; ++nt) {
      f32x4 z; z[0] = 0.f; z[1] = 0.f; z[2] = 0.f; z[3] = 0.f;
      s16x8 bk0 = *(const s16x8*)&ks[nt * 16 + lo][hi * 8];
      s16x8 bk1 = *(const s16x8*)&ks[nt * 16 + lo][32 + hi * 8];
      z = __builtin_amdgcn_mfma_f32_16x16x32_bf16(aq0, bk0, z, 0, 0, 0);
      z = __builtin_amdgcn_mfma_f32_16x16x32_bf16(aq1, bk1, z, 0, 0, 0);
      sc[nt] = z;
    }
#pragma unroll
    for (int nt = 0; nt < 4; ++nt) {
      float mv = ms[nt * 16 + lo];
      float addv = (1.f - mv) * -1e30f;
#pragma unroll
      for (int r = 0; r < 4; ++r) sc[nt][r] = sc[nt][r] * scale * mv + addv;
    }
    float alpha[4];
#pragma unroll
    for (int r = 0; r < 4; ++r) {
      float m0 = fmaxf(fmaxf(sc[0][r], sc[1][r]), fmaxf(sc[2][r], sc[3][r]));
#pragma unroll
      for (int off = 1; off < 16; off <<= 1) m0 = fmaxf(m0, __shfl_xor(m0, off));
      float mn = fmaxf(m_i[r], m0);
      alpha[r] = __expf(m_i[r] - mn);
      m_i[r] = mn;
    }
    float psum[4] = {0.f, 0.f, 0.f, 0.f};
#pragma unroll
    for (int nt = 0; nt < 4; ++nt)
#pragma unroll
      for (int r = 0; r < 4; ++r) {
        float p = __expf(sc[nt][r] - m_i[r]);
        psum[r] += p;
        ps[w][hi * 4 + r][nt * 16 + lo] = f2bf(p);
      }
#pragma unroll
    for (int r = 0; r < 4; ++r) {
      float sum = psum[r];
#pragma unroll
      for (int off = 1; off < 16; off <<= 1) sum += __shfl_xor(sum, off);
      l_i[r] = l_i[r] * alpha[r] + sum;
    }
#pragma unroll
    for (int nt = 0; nt < 4; ++nt)
#pragma unroll
      for (int r = 0; r < 4; ++r) acc[nt][r] *= alpha[r];

    s16x8 ap0 = *(const s16x8*)&ps[w][lo][hi * 8];
    s16x8 ap1 = *(const s16x8*)&ps[w][lo][32 + hi * 8];
#pragma unroll
    for (int nt = 0; nt < 4; ++nt) {
      s16x8 bv0 = *(const s16x8*)&vt[nt * 16 + lo][hi * 8];
      s16x8 bv1 = *(const s16x8*)&vt[nt * 16 + lo][32 + hi * 8];
      acc[nt] = __builtin_amdgcn_mfma_f32_16x16x32_bf16(ap0, bv0, acc[nt], 0, 0, 0);
      acc[nt] = __builtin_amdgcn_mfma_f32_16x16x32_bf16(ap1, bv1, acc[nt], 0, 0, 0);
    }
  }
#pragma unroll
  for (int r = 0; r < 4; ++r) {
    int row = qt * 32 + w * 16 + hi * 4 + r;
    size_t pb = (((size_t)b * TT + row) * NSPLIT + sp) * DK;
#pragma unroll
    for (int nt = 0; nt < 4; ++nt) pacc[pb + nt * 16 + lo] = f2bf(acc[nt][r]);
    if (lo == 0) {
      size_t mb = (((size_t)b * TT + row) * NSPLIT + sp) * 2;
      pml[mb] = m_i[r];
      pml[mb + 1] = l_i[r];
    }
  }
}

// ---------------- combine partials + heads@Wo2 (MFMA) + residual ----------------
__global__ __launch_bounds__(256) void k_attnout(const short* __restrict__ pacc,
                                                 const float* __restrict__ pml,
                                                 const float* __restrict__ mask,
                                                 const short* __restrict__ wo2b,
                                                 const short* __restrict__ res,
                                                 short* __restrict__ out,
                                                 float* __restrict__ part_out) {
  int tile = blockIdx.x & 31, b = blockIdx.x >> 5;
  int t0 = tile * 32;
  __shared__ __align__(16) short Ht[32][72];
  {
    int row = threadIdx.x >> 3, d8 = threadIdx.x & 7;
    size_t rb = (size_t)b * TT + t0 + row;
    float m[NSPLIT], l[NSPLIT];
#pragma unroll
    for (int s = 0; s < NSPLIT; ++s) {
      m[s] = pml[(rb * NSPLIT + s) * 2];
      l[s] = pml[(rb * NSPLIT + s) * 2 + 1];
    }
    float M = fmaxf(fmaxf(m[0], m[1]), fmaxf(m[2], m[3]));
    float wgt[NSPLIT], L = 0.f;
#pragma unroll
    for (int s = 0; s < NSPLIT; ++s) { wgt[s] = __expf(m[s] - M); L += wgt[s] * l[s]; }
    float inv = mask[rb] / L;
    float o[8];
#pragma unroll
    for (int j = 0; j < 8; ++j) o[j] = 0.f;
#pragma unroll
    for (int s = 0; s < NSPLIT; ++s) {
      s16x8 pv = *(const s16x8*)(pacc + (rb * NSPLIT + s) * DK + d8 * 8);
#pragma unroll
      for (int j = 0; j < 8; ++j) o[j] += wgt[s] * bf2f(pv[j]);
    }
    s16x8 hv;
#pragma unroll
    for (int j = 0; j < 8; ++j) hv[j] = f2bf(o[j] * inv);
    *(s16x8*)&Ht[row][d8 * 8] = hv;
  }
  __syncthreads();

  int w = threadIdx.x >> 6, lane = threadIdx.x & 63;
  int lo = lane & 15, hi = lane >> 4;
  f32x4 acc[2][2];
#pragma unroll
  for (int mt = 0; mt < 2; ++mt)
#pragma unroll
    for (int nt = 0; nt < 2; ++nt) { acc[mt][nt][0] = 0.f; acc[mt][nt][1] = 0.f; acc[mt][nt][2] = 0.f; acc[mt][nt][3] = 0.f; }
#pragma unroll
  for (int ks = 0; ks < 2; ++ks) {
    s16x8 b0 = *(const s16x8*)&Ht[lo][ks * 32 + hi * 8];
    s16x8 b1 = *(const s16x8*)&Ht[16 + lo][ks * 32 + hi * 8];
    s16x8 a0 = *(const s16x8*)&wo2b[(size_t)(w * 32 + lo) * DK + ks * 32 + hi * 8];
    s16x8 a1 = *(const s16x8*)&wo2b[(size_t)(w * 32 + 16 + lo) * DK + ks * 32 + hi * 8];
    acc[0][0] = __builtin_amdgcn_mfma_f32_16x16x32_bf16(a0, b0, acc[0][0], 0, 0, 0);
    acc[0][1] = __builtin_amdgcn_mfma_f32_16x16x32_bf16(a0, b1, acc[0][1], 0, 0, 0);
    acc[1][0] = __builtin_amdgcn_mfma_f32_16x16x32_bf16(a1, b0, acc[1][0], 0, 0, 0);
    acc[1][1] = __builtin_amdgcn_mfma_f32_16x16x32_bf16(a1, b1, acc[1][1], 0, 0, 0);
  }
  float s = 0.f, ss = 0.f;
#pragma unroll
  for (int mt = 0; mt < 2; ++mt)
#pragma unroll
    for (int nt = 0; nt < 2; ++nt)
#pragma unroll
      for (int r = 0; r < 4; ++r) {
        int row = w * 32 + mt * 16 + hi * 4 + r;
        int t = t0 + nt * 16 + lo;
        size_t idx = ((size_t)b * CC + row) * TT + t;
        float v = acc[mt][nt][r] + bf2f(res[idx]);
        out[idx] = f2bf(v);
        s += v; ss += v * v;
      }
  block_partial_256(s, ss, part_out + (size_t)blockIdx.x * 2);
}

// ---------------- FC (LN fused in, MFMA) + relu + residual -> d_out fp32 ----------------
__global__ __launch_bounds__(256) void k_fc(const short* __restrict__ in,
                                            const short* __restrict__ lng,
                                            const short* __restrict__ lnb,
                                            const float* __restrict__ part_in,
                                            const short* __restrict__ fcwb,
                                            const float* __restrict__ fb,
                                            float* __restrict__ out) {
  int tile = blockIdx.x & 31, b = blockIdx.x >> 5;
  int t0 = tile * 32;
  __shared__ float stats[2];
  __shared__ __align__(16) short Dt[32][136];
  ln_stats_from_parts(part_in + (size_t)b * 64, 32, stats);
  float mu = stats[0], rs = stats[1];
  for (int i = threadIdx.x; i < CC * 16; i += 256) {
    int c = i >> 4, t2 = (i & 15) * 2;
    size_t base = ((size_t)b * CC + c) * TT + t0 + t2;
    unsigned u = *(const unsigned*)(in + base);
    unsigned g = *(const unsigned*)(lng + c * TT + t0 + t2);
    unsigned bb2 = *(const unsigned*)(lnb + c * TT + t0 + t2);
    float v0 = (bf2f((short)(u & 0xFFFF)) - mu) * rs * bf2f((short)(g & 0xFFFF)) + bf2f((short)(bb2 & 0xFFFF));
    float v1 = (bf2f((short)(u >> 16)) - mu) * rs * bf2f((short)(g >> 16)) + bf2f((short)(bb2 >> 16));
    Dt[t2][c] = f2bf(v0);
    Dt[t2 + 1][c] = f2bf(v1);
  }
  __syncthreads();

  int w = threadIdx.x >> 6, lane = threadIdx.x & 63;
  int lo = lane & 15, hi = lane >> 4;
  f32x4 acc[2][2];
#pragma unroll
  for (int mt = 0; mt < 2; ++mt)
#pragma unroll
    for (int nt = 0; nt < 2; ++nt) { acc[mt][nt][0] = 0.f; acc[mt][nt][1] = 0.f; acc[mt][nt][2] = 0.f; acc[mt][nt][3] = 0.f; }
#pragma unroll
  for (int ks = 0; ks < 4; ++ks) {
    s16x8 b0 = *(const s16x8*)&Dt[lo][ks * 32 + hi * 8];
    s16x8 b1 = *(const s16x8*)&Dt[16 + lo][ks * 32 + hi * 8];
    s16x8 a0 = *(const s16x8*)&fcwb[(size_t)(w * 32 + lo) * CC + ks * 32 + hi * 8];
    s16x8 a1 = *(const s16x8*)&fcwb[(size_t)(w * 32 + 16 + lo) * CC + ks * 32 + hi * 8];
    acc[0][0] = __builtin_amdgcn_mfma_f32_16x16x32_bf16(a0, b0, acc[0][0], 0, 0, 0);
    acc[0][1] = __builtin_amdgcn_mfma_f32_16x16x32_bf16(a0, b1, acc[0][1], 0, 0, 0);
    acc[1][0] = __builtin_amdgcn_mfma_f32_16x16x32_bf16(a1, b0, acc[1][0], 0, 0, 0);
    acc[1][1] = __builtin_amdgcn_mfma_f32_16x16x32_bf16(a1, b1, acc[1][1], 0, 0, 0);
  }
#pragma unroll
  for (int mt = 0; mt < 2; ++mt)
#pragma unroll
    for (int nt = 0; nt < 2; ++nt)
#pragma unroll
      for (int r = 0; r < 4; ++r) {
        int row = w * 32 + mt * 16 + hi * 4 + r;
        int t = t0 + nt * 16 + lo;
        size_t idx = ((size_t)b * CC + row) * TT + t;
        float v = acc[mt][nt][r] + fb[row];
        v = v > 0.f ? v : 0.f;
        out[idx] = v + bf2f(in[idx]);
      }
}

extern "C" void kernel_launch(void* const* d_in, const int* in_sizes, int n_in,
                              void* d_out, int out_size, void* d_ws, size_t ws_size,
                              hipStream_t stream) {
  const float* x    = (const float*)d_in[0];
  const float* mask = (const float*)d_in[1];
  const float* dww  = (const float*)d_in[2];
  const float* dwb  = (const float*)d_in[3];
  const float* pww  = (const float*)d_in[4];
  const float* pwb  = (const float*)d_in[5];
  const float* n0g  = (const float*)d_in[6];
  const float* n0b  = (const float*)d_in[7];
  const float* nsg  = (const float*)d_in[8];
  const float* nsb  = (const float*)d_in[9];
  const float* neg_ = (const float*)d_in[10];
  const float* neb  = (const float*)d_in[11];
  const float* Wq   = (const float*)d_in[12];
  const float* Wk   = (const float*)d_in[13];
  const float* Wv   = (const float*)d_in[14];
  const float* Wo   = (const float*)d_in[15];
  const float* fcw  = (const float*)d_in[16];
  const float* fcb  = (const float*)d_in[17];
  float* out = (float*)d_out;

  float* W = (float*)d_ws;
  const size_t NBCT = (size_t)BB * CC * TT;    // 2097152
  const size_t NBTD = (size_t)BB * TT * DK;    // 1048576
  const size_t CT = (size_t)CC * TT;           // 131072
  float* PART0 = W;                  // 4096
  float* PARTS = W + 4096;           // 5120
  float* PML   = W + 9216;           // 131072
  short* OB    = (short*)(W + 140288);
  short* SB    = OB + NBCT;
  short* QB    = SB + NBCT;
  short* KB    = QB + NBTD;
  short* VT    = KB + NBTD;
  short* PACC  = VT + NBTD;          // NBTD*NSPLIT
  short* PWWB  = PACC + NBTD * NSPLIT;
  short* WQKVB = PWWB + 65536;
  short* WO2B  = WQKVB + 24576;
  short* FCWB  = WO2B + 8192;
  short* LNPB  = FCWB + 16384;       // 12*CT
  short* N0G = LNPB, *N0B = LNPB + CT;
  short* NSG0 = LNPB + 2 * CT;       // 4 stages contiguous
  short* NSB0 = LNPB + 6 * CT;
  short* NEG = LNPB + 10 * CT, *NEB = LNPB + 11 * CT;

  k_prep<<<6592, 256, 0, stream>>>(pww, Wq, Wk, Wv, Wo, fcw,
                                   n0g, n0b, nsg, nsb, neg_, neb,
                                   PWWB, WQKVB, WO2B, FCWB, LNPB);
  k_addpos<<<BB * CC, 256, 0, stream>>>(x, OB, PART0);
  k_dsconv<false, true><<<BB * 32, 256, 0, stream>>>(
      OB, N0G, N0B, PART0, 128, dww, dwb, PWWB, pwb, SB, PARTS);
  k_dsconv<true, false><<<BB * 32, 256, 0, stream>>>(
      SB, NSG0, NSB0, PARTS, 32,
      dww + 1 * CC * KK, dwb + 1 * CC, PWWB + 1 * CC * CC, pwb + 1 * CC, OB, PARTS + 1024);
  k_dsconv<true, false><<<BB * 32, 256, 0, stream>>>(
      OB, NSG0 + CT, NSB0 + CT, PARTS + 1024, 32,
      dww + 2 * CC * KK, dwb + 2 * CC, PWWB + 2 * CC * CC, pwb + 2 * CC, SB, PARTS + 2048);
  k_dsconv<true, false><<<BB * 32, 256, 0, stream>>>(
      SB, NSG0 + 2 * CT, NSB0 + 2 * CT, PARTS + 2048, 32,
      dww + 3 * CC * KK, dwb + 3 * CC, PWWB + 3 * CC * CC, pwb + 3 * CC, OB, PARTS + 3072);
  k_qkv<<<BB * 32, 256, 0, stream>>>(OB, NSG0 + 3 * CT, NSB0 + 3 * CT, PARTS + 3072,
                                     WQKVB, QB, KB, VT);
  k_attn<<<BB * 32 * NSPLIT, 128, 0, stream>>>(QB, KB, VT, mask, PACC, PML);
  k_attnout<<<BB * 32, 256, 0, stream>>>(PACC, PML, mask, WO2B, OB, SB, PARTS + 4096);
  k_fc<<<BB * 32, 256, 0, stream>>>(SB, NEG, NEB, PARTS + 4096, FCWB, fcb, out);
}

// Round 6
// 219.777 us; speedup vs baseline: 1.0424x; 1.0424x over previous
//
#include <hip/hip_runtime.h>
#include <math.h>

#define BB 16
#define CC 128
#define TT 1024
#define KK 7
#define DK 64
#define NSPLIT 4

typedef float f32x4 __attribute__((ext_vector_type(4)));
typedef short s16x8 __attribute__((ext_vector_type(8)));

__device__ inline short f2bf(float f) {
  union { float f; unsigned u; } v; v.f = f;
  unsigned r = (v.u + 0x7FFFu + ((v.u >> 16) & 1u)) >> 16;
  return (short)r;
}
__device__ inline float bf2f(short s) {
  union { unsigned u; float f; } v;
  v.u = ((unsigned)(unsigned short)s) << 16;
  return v.f;
}

// block-wide (256 threads) reduce of (s,ss) -> dst[0..1]
__device__ inline void block_partial_256(float s, float ss, float* dst) {
#pragma unroll
  for (int off = 32; off; off >>= 1) { s += __shfl_xor(s, off); ss += __shfl_xor(ss, off); }
  __shared__ float red[8];
  int w = threadIdx.x >> 6;
  if ((threadIdx.x & 63) == 0) { red[2 * w] = s; red[2 * w + 1] = ss; }
  __syncthreads();
  if (threadIdx.x == 0) {
    for (int i = 1; i < 4; ++i) { s += red[2 * i]; ss += red[2 * i + 1]; }
    dst[0] = s; dst[1] = ss;
  }
}

__device__ inline void ln_stats_from_parts(const float* part_batch, int n, float* sh) {
  if (threadIdx.x < 64) {
    float s = 0.f, ss = 0.f;
    for (int i = threadIdx.x; i < n; i += 64) { s += part_batch[2 * i]; ss += part_batch[2 * i + 1]; }
#pragma unroll
    for (int off = 32; off; off >>= 1) { s += __shfl_xor(s, off); ss += __shfl_xor(ss, off); }
    if (threadIdx.x == 0) {
      const float invN = 1.f / (float)(CC * TT);
      float mu = s * invN;
      sh[0] = mu;
      sh[1] = rsqrtf(ss * invN - mu * mu + 1e-5f);
    }
  }
  __syncthreads();
}

// ------- merged: pos-encoding+add (blocks 0..2047) and weight/LN-param prep (rest) -------
__global__ __launch_bounds__(256) void k_prep_addpos(const float* __restrict__ x,
                                                     const float* __restrict__ pww,
                                                     const float* __restrict__ Wq,
                                                     const float* __restrict__ Wk,
                                                     const float* __restrict__ Wv,
                                                     const float* __restrict__ Wo,
                                                     const float* __restrict__ fcw,
                                                     const float* __restrict__ n0g,
                                                     const float* __restrict__ n0b,
                                                     const float* __restrict__ nsg,
                                                     const float* __restrict__ nsb,
                                                     const float* __restrict__ neg_,
                                                     const float* __restrict__ neb,
                                                     short* __restrict__ out,
                                                     float* __restrict__ part,
                                                     short* __restrict__ pwwb,
                                                     short* __restrict__ wqkvb,
                                                     short* __restrict__ wo2b,
                                                     short* __restrict__ fcwb,
                                                     short* __restrict__ lnpb) {
  if (blockIdx.x < BB * CC) {
    int bc = blockIdx.x;
    int c = bc & (CC - 1);
    float ce = (float)(c & ~1);
    float freq = expf(-(ce / (float)CC) * 9.210340371976184f);
    float phase = (c & 1) ? 1.5707963267948966f : 0.0f;
    const float4* xr = (const float4*)(x + (size_t)bc * TT);
    short* orow = out + (size_t)bc * TT;
    int t = threadIdx.x * 4;
    float4 xv = xr[threadIdx.x];
    float v0 = xv.x + sinf((float)t * freq + phase);
    float v1 = xv.y + sinf((float)(t + 1) * freq + phase);
    float v2 = xv.z + sinf((float)(t + 2) * freq + phase);
    float v3 = xv.w + sinf((float)(t + 3) * freq + phase);
    float s = v0 + v1 + v2 + v3;
    float ss = v0 * v0 + v1 * v1 + v2 * v2 + v3 * v3;
    short4 o; o.x = f2bf(v0); o.y = f2bf(v1); o.z = f2bf(v2); o.w = f2bf(v3);
    *(short4*)(orow + t) = o;
    block_partial_256(s, ss, part + (size_t)bc * 2);
    return;
  }
  int i = (blockIdx.x - BB * CC) * 256 + threadIdx.x;
  if (i < 65536) { pwwb[i] = f2bf(pww[i]); return; }
  i -= 65536;
  if (i < 24576) {  // wqkvb[m][c] = W{q,k,v}[c][m&63]
    int m = i >> 7, c = i & 127;
    int sel = m >> 6, d = m & 63;
    const float* srcp = sel == 0 ? Wq : (sel == 1 ? Wk : Wv);
    wqkvb[i] = f2bf(srcp[c * DK + d]);
    return;
  }
  i -= 24576;
  if (i < 8192) {  // wo2b[o][d] = Wo[d][o] + Wo[d+64][o]
    int o = i >> 6, d = i & 63;
    wo2b[i] = f2bf(Wo[d * CC + o] + Wo[(d + 64) * CC + o]);
    return;
  }
  i -= 8192;
  if (i < 16384) { fcwb[i] = f2bf(fcw[i]); return; }
  i -= 16384;
  if (i >= 1572864) return;
  const int CT = CC * TT;
  float v;
  if (i < CT) v = n0g[i];
  else if (i < 2 * CT) v = n0b[i - CT];
  else if (i < 6 * CT) v = nsg[i - 2 * CT];
  else if (i < 10 * CT) v = nsb[i - 6 * CT];
  else if (i < 11 * CT) v = neg_[i - 10 * CT];
  else v = neb[i - 11 * CT];
  lnpb[i] = f2bf(v);
}

// ------- dsconv, 16-wide tile: [LN-in] depthwise(fp32) -> MFMA pointwise + relu + [LN-res] res -------
template <bool LN_IN, bool LN_RES>
__global__ __launch_bounds__(256) void k_dsconv(const short* __restrict__ in,
                                                const short* __restrict__ lng,
                                                const short* __restrict__ lnb,
                                                const float* __restrict__ part_in, int npart,
                                                const float* __restrict__ dww,
                                                const float* __restrict__ dwb,
                                                const short* __restrict__ pwwb,
                                                const float* __restrict__ pwb,
                                                short* __restrict__ out,
                                                float* __restrict__ part_out) {
  int tile = blockIdx.x & 63, b = blockIdx.x >> 6;
  int t0 = tile * 16;
  __shared__ float stats[2];
  __shared__ float xs[CC][33];                // window [t0-8, t0+24), stride 33 (odd)
  __shared__ __align__(16) short Dt[16][136]; // depthwise out, transposed [t][c]
  ln_stats_from_parts(part_in + (size_t)b * npart * 2, npart, stats);
  float mu = stats[0], rs = stats[1];

  // staging: 128 rows x 4 chunks of 8 bf16 (chunks never straddle [0,TT))
  for (int ch = threadIdx.x; ch < 512; ch += 256) {
    int c = ch >> 2, half = ch & 3;
    int ts = t0 - 8 + half * 8;
    float v[8];
    if (ts >= 0 && ts < TT) {
      size_t base = ((size_t)b * CC + c) * TT + ts;
      s16x8 raw = *(const s16x8*)(in + base);
      if (LN_IN) {
        s16x8 g = *(const s16x8*)(lng + c * TT + ts);
        s16x8 bb = *(const s16x8*)(lnb + c * TT + ts);
#pragma unroll
        for (int j = 0; j < 8; ++j)
          v[j] = (bf2f(raw[j]) - mu) * rs * bf2f(g[j]) + bf2f(bb[j]);
      } else {
#pragma unroll
        for (int j = 0; j < 8; ++j) v[j] = bf2f(raw[j]);
      }
    } else {
#pragma unroll
      for (int j = 0; j < 8; ++j) v[j] = 0.f;
    }
#pragma unroll
    for (int j = 0; j < 8; ++j) xs[c][half * 8 + j] = v[j];
  }
  __syncthreads();
  // depthwise: output t local 0..15 -> window index t+5..t+11
  for (int i = threadIdx.x; i < 16 * CC; i += 256) {
    int t = i >> 7, c = i & 127;
    float a = dwb[c];
#pragma unroll
    for (int j = 0; j < KK; ++j) a += dww[c * KK + j] * xs[c][t + 5 + j];
    Dt[t][c] = f2bf(a);
  }
  __syncthreads();

  int w = threadIdx.x >> 6, lane = threadIdx.x & 63;
  int lo = lane & 15, hi = lane >> 4;
  f32x4 acc[2];
#pragma unroll
  for (int mt = 0; mt < 2; ++mt) { acc[mt][0] = 0.f; acc[mt][1] = 0.f; acc[mt][2] = 0.f; acc[mt][3] = 0.f; }
#pragma unroll
  for (int ks = 0; ks < 4; ++ks) {
    s16x8 b0 = *(const s16x8*)&Dt[lo][ks * 32 + hi * 8];
    s16x8 a0 = *(const s16x8*)&pwwb[(size_t)(w * 32 + lo) * CC + ks * 32 + hi * 8];
    s16x8 a1 = *(const s16x8*)&pwwb[(size_t)(w * 32 + 16 + lo) * CC + ks * 32 + hi * 8];
    acc[0] = __builtin_amdgcn_mfma_f32_16x16x32_bf16(a0, b0, acc[0], 0, 0, 0);
    acc[1] = __builtin_amdgcn_mfma_f32_16x16x32_bf16(a1, b0, acc[1], 0, 0, 0);
  }

  float s = 0.f, ss = 0.f;
#pragma unroll
  for (int mt = 0; mt < 2; ++mt)
#pragma unroll
    for (int r = 0; r < 4; ++r) {
      int row = w * 32 + mt * 16 + hi * 4 + r;
      int t = t0 + lo;
      float v = acc[mt][r] + pwb[row];
      v = v > 0.f ? v : 0.f;
      size_t idx = ((size_t)b * CC + row) * TT + t;
      float rv = bf2f(in[idx]);
      if (LN_RES) rv = (rv - mu) * rs * bf2f(lng[row * TT + t]) + bf2f(lnb[row * TT + t]);
      v += rv;
      out[idx] = f2bf(v);
      s += v; ss += v * v;
    }
  block_partial_256(s, ss, part_out + (size_t)blockIdx.x * 2);
}

// ---------------- q,k,v projections: MFMA, M=192 stacked, 16-wide tile ----------------
__global__ __launch_bounds__(256) void k_qkv(const short* __restrict__ in,
                                             const short* __restrict__ lng,
                                             const short* __restrict__ lnb,
                                             const float* __restrict__ part_in, int npart,
                                             const short* __restrict__ wqkvb,
                                             short* __restrict__ q,
                                             short* __restrict__ k,
                                             short* __restrict__ vt) {
  int tile = blockIdx.x & 63, b = blockIdx.x >> 6;
  int t0 = tile * 16;
  __shared__ float stats[2];
  __shared__ __align__(16) short Dt[16][136];
  ln_stats_from_parts(part_in + (size_t)b * npart * 2, npart, stats);
  float mu = stats[0], rs = stats[1];
  {
    int i = threadIdx.x;  // 256 = 128 rows x 2 chunks of 8
    int c = i >> 1, half = i & 1;
    int ts = t0 + half * 8;
    size_t base = ((size_t)b * CC + c) * TT + ts;
    s16x8 raw = *(const s16x8*)(in + base);
    s16x8 g = *(const s16x8*)(lng + c * TT + ts);
    s16x8 bb = *(const s16x8*)(lnb + c * TT + ts);
#pragma unroll
    for (int j = 0; j < 8; ++j)
      Dt[half * 8 + j][c] = f2bf((bf2f(raw[j]) - mu) * rs * bf2f(g[j]) + bf2f(bb[j]));
  }
  __syncthreads();

  int w = threadIdx.x >> 6, lane = threadIdx.x & 63;
  int lo = lane & 15, hi = lane >> 4;
  f32x4 acc[3];
#pragma unroll
  for (int mt = 0; mt < 3; ++mt) { acc[mt][0] = 0.f; acc[mt][1] = 0.f; acc[mt][2] = 0.f; acc[mt][3] = 0.f; }
#pragma unroll
  for (int ks = 0; ks < 4; ++ks) {
    s16x8 b0 = *(const s16x8*)&Dt[lo][ks * 32 + hi * 8];
#pragma unroll
    for (int mt = 0; mt < 3; ++mt) {
      s16x8 a = *(const s16x8*)&wqkvb[(size_t)(w * 48 + mt * 16 + lo) * CC + ks * 32 + hi * 8];
      acc[mt] = __builtin_amdgcn_mfma_f32_16x16x32_bf16(a, b0, acc[mt], 0, 0, 0);
    }
  }
#pragma unroll
  for (int mt = 0; mt < 3; ++mt) {
    int m0 = w * 48 + mt * 16 + hi * 4;
    int t = t0 + lo;
    short4 pk;
    pk.x = f2bf(acc[mt][0]); pk.y = f2bf(acc[mt][1]);
    pk.z = f2bf(acc[mt][2]); pk.w = f2bf(acc[mt][3]);
    if (m0 < 64) {
      *(short4*)(q + ((size_t)b * TT + t) * DK + m0) = pk;
    } else if (m0 < 128) {
      *(short4*)(k + ((size_t)b * TT + t) * DK + (m0 - 64)) = pk;
    } else {
      int d = m0 - 128;
      vt[((size_t)b * DK + d) * TT + t] = pk.x;
      vt[((size_t)b * DK + d + 1) * TT + t] = pk.y;
      vt[((size_t)b * DK + d + 2) * TT + t] = pk.z;
      vt[((size_t)b * DK + d + 3) * TT + t] = pk.w;
    }
  }
}

// ------- flash attention split-K; K/V B-frags loaded direct from global (no LDS, no barriers) -------
__global__ __launch_bounds__(128) void k_attn(const short* __restrict__ qb,
                                              const short* __restrict__ kbuf,
                                              const short* __restrict__ vtb,
                                              const float* __restrict__ mask,
                                              short* __restrict__ pacc,
                                              float* __restrict__ pml) {
  int sp = blockIdx.x & (NSPLIT - 1);
  int qt = (blockIdx.x >> 2) & 31;
  int b = blockIdx.x >> 7;
  int w = threadIdx.x >> 6, lane = threadIdx.x & 63;
  int lo = lane & 15, hi = lane >> 4;

  __shared__ __align__(16) short ps[2][16][72];  // wave-private P round-trip

  const short* qp = qb + ((size_t)b * TT + qt * 32 + w * 16 + lo) * DK + hi * 8;
  s16x8 aq0 = *(const s16x8*)qp;
  s16x8 aq1 = *(const s16x8*)(qp + 32);

  f32x4 acc[4];
  float m_i[4], l_i[4];
#pragma unroll
  for (int r = 0; r < 4; ++r) {
    m_i[r] = -3.0e38f; l_i[r] = 0.f;
#pragma unroll
    for (int nt = 0; nt < 4; ++nt) acc[nt][r] = 0.f;
  }
  const float scale = 0.125f;

  for (int kb2 = sp * (TT / 64 / NSPLIT); kb2 < (sp + 1) * (TT / 64 / NSPLIT); ++kb2) {
    f32x4 sc[4];
    float mv[4];
#pragma unroll
    for (int nt = 0; nt < 4; ++nt) {
      const short* kp = kbuf + ((size_t)b * TT + kb2 * 64 + nt * 16 + lo) * DK + hi * 8;
      s16x8 bk0 = *(const s16x8*)kp;
      s16x8 bk1 = *(const s16x8*)(kp + 32);
      f32x4 z; z[0] = 0.f; z[1] = 0.f; z[2] = 0.f; z[3] = 0.f;
      z = __builtin_amdgcn_mfma_f32_16x16x32_bf16(aq0, bk0, z, 0, 0, 0);
      z = __builtin_amdgcn_mfma_f32_16x16x32_bf16(aq1, bk1, z, 0, 0, 0);
      sc[nt] = z;
      mv[nt] = mask[(size_t)b * TT + kb2 * 64 + nt * 16 + lo];
    }
#pragma unroll
    for (int nt = 0; nt < 4; ++nt) {
      float addv = (1.f - mv[nt]) * -1e30f;
#pragma unroll
      for (int r = 0; r < 4; ++r) sc[nt][r] = sc[nt][r] * scale * mv[nt] + addv;
    }
    float alpha[4];
#pragma unroll
    for (int r = 0; r < 4; ++r) {
      float m0 = fmaxf(fmaxf(sc[0][r], sc[1][r]), fmaxf(sc[2][r], sc[3][r]));
#pragma unroll
      for (int off = 1; off < 16; off <<= 1) m0 = fmaxf(m0, __shfl_xor(m0, off));
      float mn = fmaxf(m_i[r], m0);
      alpha[r] = __expf(m_i[r] - mn);
      m_i[r] = mn;
    }
    float psum[4] = {0.f, 0.f, 0.f, 0.f};
#pragma unroll
    for (int nt = 0; nt < 4; ++nt)
#pragma unroll
      for (int r = 0; r < 4; ++r) {
        float p = __expf(sc[nt][r] - m_i[r]);
        psum[r] += p;
        ps[w][hi * 4 + r][nt * 16 + lo] = f2bf(p);
      }
#pragma unroll
    for (int r = 0; r < 4; ++r) {
      float sum = psum[r];
#pragma unroll
      for (int off = 1; off < 16; off <<= 1) sum += __shfl_xor(sum, off);
      l_i[r] = l_i[r] * alpha[r] + sum;
    }
#pragma unroll
    for (int nt = 0; nt < 4; ++nt)
#pragma unroll
      for (int r = 0; r < 4; ++r) acc[nt][r] *= alpha[r];

    s16x8 ap0 = *(const s16x8*)&ps[w][lo][hi * 8];
    s16x8 ap1 = *(const s16x8*)&ps[w][lo][32 + hi * 8];
#pragma unroll
    for (int nt = 0; nt < 4; ++nt) {
      const short* vp = vtb + ((size_t)b * DK + nt * 16 + lo) * TT + kb2 * 64 + hi * 8;
      s16x8 bv0 = *(const s16x8*)vp;
      s16x8 bv1 = *(const s16x8*)(vp + 32);
      acc[nt] = __builtin_amdgcn_mfma_f32_16x16x32_bf16(ap0, bv0, acc[nt], 0, 0, 0);
      acc[nt] = __builtin_amdgcn_mfma_f32_16x16x32_bf16(ap1, bv1, acc[nt], 0, 0, 0);
    }
  }
#pragma unroll
  for (int r = 0; r < 4; ++r) {
    int row = qt * 32 + w * 16 + hi * 4 + r;
    size_t pb = (((size_t)b * TT + row) * NSPLIT + sp) * DK;
#pragma unroll
    for (int nt = 0; nt < 4; ++nt) pacc[pb + nt * 16 + lo] = f2bf(acc[nt][r]);
    if (lo == 0) {
      size_t mb = (((size_t)b * TT + row) * NSPLIT + sp) * 2;
      pml[mb] = m_i[r];
      pml[mb + 1] = l_i[r];
    }
  }
}

// ------- combine partials + heads@Wo2 (MFMA) + residual, 16-wide tile -------
__global__ __launch_bounds__(256) void k_attnout(const short* __restrict__ pacc,
                                                 const float* __restrict__ pml,
                                                 const float* __restrict__ mask,
                                                 const short* __restrict__ wo2b,
                                                 const short* __restrict__ res,
                                                 short* __restrict__ out,
                                                 float* __restrict__ part_out) {
  int tile = blockIdx.x & 63, b = blockIdx.x >> 6;
  int t0 = tile * 16;
  __shared__ __align__(16) short Ht[16][72];
  if (threadIdx.x < 128) {
    int row = threadIdx.x >> 3, d8 = threadIdx.x & 7;
    size_t rb = (size_t)b * TT + t0 + row;
    float m[NSPLIT], l[NSPLIT];
#pragma unroll
    for (int s = 0; s < NSPLIT; ++s) {
      m[s] = pml[(rb * NSPLIT + s) * 2];
      l[s] = pml[(rb * NSPLIT + s) * 2 + 1];
    }
    float M = fmaxf(fmaxf(m[0], m[1]), fmaxf(m[2], m[3]));
    float wgt[NSPLIT], L = 0.f;
#pragma unroll
    for (int s = 0; s < NSPLIT; ++s) { wgt[s] = __expf(m[s] - M); L += wgt[s] * l[s]; }
    float inv = mask[rb] / L;
    float o[8];
#pragma unroll
    for (int j = 0; j < 8; ++j) o[j] = 0.f;
#pragma unroll
    for (int s = 0; s < NSPLIT; ++s) {
      s16x8 pv = *(const s16x8*)(pacc + (rb * NSPLIT + s) * DK + d8 * 8);
#pragma unroll
      for (int j = 0; j < 8; ++j) o[j] += wgt[s] * bf2f(pv[j]);
    }
    s16x8 hv;
#pragma unroll
    for (int j = 0; j < 8; ++j) hv[j] = f2bf(o[j] * inv);
    *(s16x8*)&Ht[row][d8 * 8] = hv;
  }
  __syncthreads();

  int w = threadIdx.x >> 6, lane = threadIdx.x & 63;
  int lo = lane & 15, hi = lane >> 4;
  f32x4 acc[2];
#pragma unroll
  for (int mt = 0; mt < 2; ++mt) { acc[mt][0] = 0.f; acc[mt][1] = 0.f; acc[mt][2] = 0.f; acc[mt][3] = 0.f; }
#pragma unroll
  for (int ks = 0; ks < 2; ++ks) {
    s16x8 b0 = *(const s16x8*)&Ht[lo][ks * 32 + hi * 8];
    s16x8 a0 = *(const s16x8*)&wo2b[(size_t)(w * 32 + lo) * DK + ks * 32 + hi * 8];
    s16x8 a1 = *(const s16x8*)&wo2b[(size_t)(w * 32 + 16 + lo) * DK + ks * 32 + hi * 8];
    acc[0] = __builtin_amdgcn_mfma_f32_16x16x32_bf16(a0, b0, acc[0], 0, 0, 0);
    acc[1] = __builtin_amdgcn_mfma_f32_16x16x32_bf16(a1, b0, acc[1], 0, 0, 0);
  }
  float s = 0.f, ss = 0.f;
#pragma unroll
  for (int mt = 0; mt < 2; ++mt)
#pragma unroll
    for (int r = 0; r < 4; ++r) {
      int row = w * 32 + mt * 16 + hi * 4 + r;
      int t = t0 + lo;
      size_t idx = ((size_t)b * CC + row) * TT + t;
      float v = acc[mt][r] + bf2f(res[idx]);
      out[idx] = f2bf(v);
      s += v; ss += v * v;
    }
  block_partial_256(s, ss, part_out + (size_t)blockIdx.x * 2);
}

// ---------------- FC (LN fused in, MFMA) + relu + residual -> d_out fp32, 16-wide tile ----------------
__global__ __launch_bounds__(256) void k_fc(const short* __restrict__ in,
                                            const short* __restrict__ lng,
                                            const short* __restrict__ lnb,
                                            const float* __restrict__ part_in, int npart,
                                            const short* __restrict__ fcwb,
                                            const float* __restrict__ fb,
                                            float* __restrict__ out) {
  int tile = blockIdx.x & 63, b = blockIdx.x >> 6;
  int t0 = tile * 16;
  __shared__ float stats[2];
  __shared__ __align__(16) short Dt[16][136];
  ln_stats_from_parts(part_in + (size_t)b * npart * 2, npart, stats);
  float mu = stats[0], rs = stats[1];
  {
    int i = threadIdx.x;
    int c = i >> 1, half = i & 1;
    int ts = t0 + half * 8;
    size_t base = ((size_t)b * CC + c) * TT + ts;
    s16x8 raw = *(const s16x8*)(in + base);
    s16x8 g = *(const s16x8*)(lng + c * TT + ts);
    s16x8 bb = *(const s16x8*)(lnb + c * TT + ts);
#pragma unroll
    for (int j = 0; j < 8; ++j)
      Dt[half * 8 + j][c] = f2bf((bf2f(raw[j]) - mu) * rs * bf2f(g[j]) + bf2f(bb[j]));
  }
  __syncthreads();

  int w = threadIdx.x >> 6, lane = threadIdx.x & 63;
  int lo = lane & 15, hi = lane >> 4;
  f32x4 acc[2];
#pragma unroll
  for (int mt = 0; mt < 2; ++mt) { acc[mt][0] = 0.f; acc[mt][1] = 0.f; acc[mt][2] = 0.f; acc[mt][3] = 0.f; }
#pragma unroll
  for (int ks = 0; ks < 4; ++ks) {
    s16x8 b0 = *(const s16x8*)&Dt[lo][ks * 32 + hi * 8];
    s16x8 a0 = *(const s16x8*)&fcwb[(size_t)(w * 32 + lo) * CC + ks * 32 + hi * 8];
    s16x8 a1 = *(const s16x8*)&fcwb[(size_t)(w * 32 + 16 + lo) * CC + ks * 32 + hi * 8];
    acc[0] = __builtin_amdgcn_mfma_f32_16x16x32_bf16(a0, b0, acc[0], 0, 0, 0);
    acc[1] = __builtin_amdgcn_mfma_f32_16x16x32_bf16(a1, b0, acc[1], 0, 0, 0);
  }
#pragma unroll
  for (int mt = 0; mt < 2; ++mt)
#pragma unroll
    for (int r = 0; r < 4; ++r) {
      int row = w * 32 + mt * 16 + hi * 4 + r;
      int t = t0 + lo;
      size_t idx = ((size_t)b * CC + row) * TT + t;
      float v = acc[mt][r] + fb[row];
      v = v > 0.f ? v : 0.f;
      out[idx] = v + bf2f(in[idx]);
    }
}

extern "C" void kernel_launch(void* const* d_in, const int* in_sizes, int n_in,
                              void* d_out, int out_size, void* d_ws, size_t ws_size,
                              hipStream_t stream) {
  const float* x    = (const float*)d_in[0];
  const float* mask = (const float*)d_in[1];
  const float* dww  = (const float*)d_in[2];
  const float* dwb  = (const float*)d_in[3];
  const float* pww  = (const float*)d_in[4];
  const float* pwb  = (const float*)d_in[5];
  const float* n0g  = (const float*)d_in[6];
  const float* n0b  = (const float*)d_in[7];
  const float* nsg  = (const float*)d_in[8];
  const float* nsb  = (const float*)d_in[9];
  const float* neg_ = (const float*)d_in[10];
  const float* neb  = (const float*)d_in[11];
  const float* Wq   = (const float*)d_in[12];
  const float* Wk   = (const float*)d_in[13];
  const float* Wv   = (const float*)d_in[14];
  const float* Wo   = (const float*)d_in[15];
  const float* fcw  = (const float*)d_in[16];
  const float* fcb  = (const float*)d_in[17];
  float* out = (float*)d_out;

  float* W = (float*)d_ws;
  const size_t NBCT = (size_t)BB * CC * TT;    // 2097152
  const size_t NBTD = (size_t)BB * TT * DK;    // 1048576
  const size_t CT = (size_t)CC * TT;           // 131072
  float* PART0 = W;                  // 4096 floats (addpos, 128/batch)
  float* PARTS = W + 4096;           // 5 stages x 2048 floats (64/batch)
  float* PML   = W + 4096 + 5 * 2048;   // BB*TT*NSPLIT*2 = 131072
  short* OB    = (short*)(PML + 131072);
  short* SB    = OB + NBCT;
  short* QB    = SB + NBCT;
  short* KB    = QB + NBTD;
  short* VT    = KB + NBTD;
  short* PACC  = VT + NBTD;          // NBTD*NSPLIT
  short* PWWB  = PACC + NBTD * NSPLIT;
  short* WQKVB = PWWB + 65536;
  short* WO2B  = WQKVB + 24576;
  short* FCWB  = WO2B + 8192;
  short* LNPB  = FCWB + 16384;       // 12*CT
  short* N0G = LNPB, *N0B = LNPB + CT;
  short* NSG0 = LNPB + 2 * CT;
  short* NSB0 = LNPB + 6 * CT;
  short* NEG = LNPB + 10 * CT, *NEB = LNPB + 11 * CT;

  k_prep_addpos<<<BB * CC + 6592, 256, 0, stream>>>(
      x, pww, Wq, Wk, Wv, Wo, fcw, n0g, n0b, nsg, nsb, neg_, neb,
      OB, PART0, PWWB, WQKVB, WO2B, FCWB, LNPB);
  k_dsconv<false, true><<<BB * 64, 256, 0, stream>>>(
      OB, N0G, N0B, PART0, 128, dww, dwb, PWWB, pwb, SB, PARTS);
  k_dsconv<true, false><<<BB * 64, 256, 0, stream>>>(
      SB, NSG0, NSB0, PARTS, 64,
      dww + 1 * CC * KK, dwb + 1 * CC, PWWB + 1 * CC * CC, pwb + 1 * CC, OB, PARTS + 2048);
  k_dsconv<true, false><<<BB * 64, 256, 0, stream>>>(
      OB, NSG0 + CT, NSB0 + CT, PARTS + 2048, 64,
      dww + 2 * CC * KK, dwb + 2 * CC, PWWB + 2 * CC * CC, pwb + 2 * CC, SB, PARTS + 4096);
  k_dsconv<true, false><<<BB * 64, 256, 0, stream>>>(
      SB, NSG0 + 2 * CT, NSB0 + 2 * CT, PARTS + 4096, 64,
      dww + 3 * CC * KK, dwb + 3 * CC, PWWB + 3 * CC * CC, pwb + 3 * CC, OB, PARTS + 6144);
  k_qkv<<<BB * 64, 256, 0, stream>>>(OB, NSG0 + 3 * CT, NSB0 + 3 * CT, PARTS + 6144, 64,
                                     WQKVB, QB, KB, VT);
  k_attn<<<BB * 32 * NSPLIT, 128, 0, stream>>>(QB, KB, VT, mask, PACC, PML);
  k_attnout<<<BB * 64, 256, 0, stream>>>(PACC, PML, mask, WO2B, OB, SB, PARTS + 8192);
  k_fc<<<BB * 64, 256, 0, stream>>>(SB, NEG, NEB, PARTS + 8192, 64, FCWB, fcb, out);
}